// Round 10
// baseline (323.768 us; speedup 1.0000x reference)
//
#include <hip/hip_runtime.h>

#pragma clang fp contract(off)

#define NA 131072
#define NC 8
#define NK 2048
#define CAP 8192       // max keys per class = NSEG*SEGC
#define NSEG 128       // scan blocks / per-class segments
#define SEGC 64        // per-segment key capacity (mean 10.2, +17 sigma)
#define NW 32
#define NB 256         // rank buckets (164 used by score range)
#define CONF 0.99f
#define IMGW 320.0f
#define IMGH 256.0f

typedef unsigned long long u64;

// ---------------- ws layout (bytes) ----------------
// bcnt : NC*NSEG int      @ 0     (4 KB)
// vkey : NC*NSEG*SEGC u64 @ 4096  (512 KB)

// Monotonic bucket index: higher score -> lower bucket. Scores in (0.99,1.0)
// share exponent 126, so bits(1.0)-bits(s) is monotone; >>10 gives 0..163.
__device__ __forceinline__ int bucket_of(unsigned sb) {
    int d = (int)(0x3F800000u - sb);
    return min(max(d >> 10, 0), NB - 1);
}

// Exact-decision IoU > 0.5, usually division-free (absmax 0.0 r4-r9).
__device__ __forceinline__ bool iou_gt(float bix, float biy, float biz, float biw, float ai,
                                       float bjx, float bjy, float bjz, float bjw, float aj) {
    float xx1 = fmaxf(bix, bjx), yy1 = fmaxf(biy, bjy);
    float xx2 = fminf(biz, bjz), yy2 = fminf(biw, bjw);
    float inter = fmaxf(xx2 - xx1, 0.0f) * fmaxf(yy2 - yy1, 0.0f);
    float uni = (ai + aj) - inter;
    float th = 0.5f * uni;
    float diff = inter - th;
    bool pred = diff > 0.0f;
    if (__builtin_expect((uni < 1e-8f) || (pred && diff < th * 1e-6f), 0)) {
        pred = (inter / fmaxf(uni, 1e-8f)) > 0.5f;
    }
    return pred;
}

__device__ __forceinline__ float rdlane(float v, int l) {
    return __uint_as_float((unsigned)__builtin_amdgcn_readlane(__float_as_int(v), l));
}

// Atomic-free scan: block b writes its class-c hits into segment (c,b) plus a
// per-segment count. No global atomics, no init kernel needed.
__global__ __launch_bounds__(1024) void k_scan(const float* __restrict__ cls,
                                               int* __restrict__ bcnt,
                                               u64* __restrict__ vkey) {
    __shared__ int wcnt[NC][16];
    __shared__ int woff[NC][16];
    int tid = threadIdx.x;
    int lane = tid & 63;
    int wid = tid >> 6;
    int a = blockIdx.x * 1024 + tid;

    const float4* c4 = (const float4*)(cls + (size_t)a * NC);
    float4 s0 = c4[0], s1 = c4[1];
    float sc[8] = {s0.x, s0.y, s0.z, s0.w, s1.x, s1.y, s1.z, s1.w};

    bool hit[NC];
    int off[NC];
    #pragma unroll
    for (int c = 0; c < NC; ++c) {
        bool p = sc[c] > CONF;
        u64 m = __ballot(p);
        hit[c] = p;
        off[c] = (int)__popcll(m & ((1ULL << lane) - 1ULL));
        if (lane == 0) wcnt[c][wid] = (int)__popcll(m);
    }
    __syncthreads();

    if (wid < NC) {   // wave w scans class w's 16 wave-counts
        int c = wid;
        int v = (lane < 16) ? wcnt[c][lane] : 0;
        #pragma unroll
        for (int d = 1; d < 16; d <<= 1) {
            int y = __shfl_up(v, d);
            if (lane >= d) v += y;
        }
        if (lane < 16) woff[c][lane] = v - wcnt[c][lane];
        if (lane == 15) bcnt[c * NSEG + blockIdx.x] = min(v, SEGC);
    }
    __syncthreads();

    #pragma unroll
    for (int c = 0; c < NC; ++c) {
        if (hit[c]) {
            int pos = woff[c][wid] + off[c];
            if (pos < SEGC) {
                vkey[((size_t)c * NSEG + blockIdx.x) * SEGC + pos] =
                    ((u64)__float_as_uint(sc[c]) << 32) | (unsigned)(~a);
            }
        }
    }
}

// Per-class fused: segment gather -> counting-rank -> lazy decode ->
// intra masks (readlane) -> bitmask greedy + readlane apply -> write.
// Inner loops use v_readlane (per-SIMD VALU) instead of LDS broadcasts.
__global__ __launch_bounds__(1024) void k_nms(const int* __restrict__ bcnt,
                                              const u64* __restrict__ vkey,
                                              const float4* __restrict__ anc,
                                              const float4* __restrict__ reg,
                                              float* __restrict__ out) {
    __shared__ u64 skv[CAP];        // 64 KB bucket-segmented keys
    __shared__ float4 bxs[NK];      // 32 KB boxes in rank order
    __shared__ float bar[NK];       // 8 KB areas
    __shared__ float ssc[NK];       // 8 KB scores
    __shared__ u64 intra[NK];       // 16 KB in-chunk suppression words
    __shared__ int segcnt[NSEG];
    __shared__ int hist[NB];
    __shared__ int basep[NB];
    __shared__ int bcnt2[NB];
    __shared__ u64 remv[NW];
    __shared__ u64 keptw[NW];
    __shared__ int M_sh;

    int c = blockIdx.x;
    int tid = threadIdx.x;
    int lane = tid & 63;
    int wid = tid >> 6;

    // ---- phase 0: segment counts + zero ----
    if (tid < NSEG) segcnt[tid] = bcnt[c * NSEG + tid];
    for (int i = tid; i < NB; i += 1024) { hist[i] = 0; bcnt2[i] = 0; }
    if (tid < NW) { remv[tid] = 0ULL; keptw[tid] = 0ULL; }
    __syncthreads();

    // ---- phase 1: bucket histogram (global segment reads) ----
    for (int s = wid; s < NSEG; s += 16) {
        if (lane < segcnt[s]) {
            u64 ke = vkey[((size_t)c * NSEG + s) * SEGC + lane];
            atomicAdd(&hist[bucket_of((unsigned)(ke >> 32))], 1);
        }
    }
    __syncthreads();

    // ---- phase 2: exclusive prefix over buckets (wave 0) ----
    if (wid == 0) {
        int h0 = hist[4 * lane + 0], h1 = hist[4 * lane + 1];
        int h2 = hist[4 * lane + 2], h3 = hist[4 * lane + 3];
        int lsum = h0 + h1 + h2 + h3;
        int x = lsum;
        #pragma unroll
        for (int d = 1; d < 64; d <<= 1) {
            int y = __shfl_up(x, d);
            if (lane >= d) x += y;
        }
        int excl = x - lsum;
        basep[4 * lane + 0] = excl;
        basep[4 * lane + 1] = excl + h0;
        basep[4 * lane + 2] = excl + h0 + h1;
        basep[4 * lane + 3] = excl + h0 + h1 + h2;
        if (lane == 63) M_sh = x;
    }
    __syncthreads();
    int M = M_sh;                 // <= NSEG*SEGC = CAP
    int meff = min(M, NK);

    // ---- phase 3: scatter keys into bucket segments ----
    for (int s = wid; s < NSEG; s += 16) {
        if (lane < segcnt[s]) {
            u64 ke = vkey[((size_t)c * NSEG + s) * SEGC + lane];
            int b = bucket_of((unsigned)(ke >> 32));
            int pos = basep[b] + atomicAdd(&bcnt2[b], 1);
            skv[pos] = ke;
        }
    }
    __syncthreads();

    // ---- phase 4: exact rank (bucket base + #larger in bucket) + decode ----
    for (int p = tid; p < M; p += 1024) {
        u64 ke = skv[p];
        int b = bucket_of((unsigned)(ke >> 32));
        int st = basep[b], ln = hist[b];
        int rank = st;
        for (int q = st; q < st + ln; ++q) rank += (skv[q] > ke);
        if (rank < NK) {
            int idx = (int)(~(unsigned)ke);
            float4 av = anc[idx];
            float4 rv = reg[idx];
            float wa = av.z - av.x, ha = av.w - av.y;
            float cxa = av.x + 0.5f * wa, cya = av.y + 0.5f * ha;
            float dx = rv.x * 0.1f, dy = rv.y * 0.1f;
            float dw = rv.z * 0.2f, dh = rv.w * 0.2f;
            float pcx = cxa + dx * wa, pcy = cya + dy * ha;
            float pw = expf(dw) * wa, ph = expf(dh) * ha;
            float4 bb;
            bb.x = fmaxf(pcx - 0.5f * pw, 0.0f);
            bb.y = fmaxf(pcy - 0.5f * ph, 0.0f);
            bb.z = fminf(pcx + 0.5f * pw, IMGW);
            bb.w = fminf(pcy + 0.5f * ph, IMGH);
            bxs[rank] = bb;
            bar[rank] = fmaxf(bb.z - bb.x, 0.0f) * fmaxf(bb.w - bb.y, 0.0f);
            ssc[rank] = __uint_as_float((unsigned)(ke >> 32));
        }
    }
    __syncthreads();

    int nchunk = (meff + 63) >> 6;

    // ---- phase 5: intra-chunk words via immediate readlane (no LDS in loop) ----
    for (int cc = wid; cc < nchunk; cc += 16) {
        int base = cc << 6;
        int col = base + lane;              // < NK always
        float4 cb = bxs[col];               // 2 LDS wave-ops per chunk-visit
        float ca = bar[col];
        bool incol = col < meff;
        u64 myrow = 0ULL;
        #pragma unroll
        for (int rr = 0; rr < 64; ++rr) {
            float px1 = rdlane(cb.x, rr), py1 = rdlane(cb.y, rr);
            float px2 = rdlane(cb.z, rr), py2 = rdlane(cb.w, rr);
            float pa  = rdlane(ca, rr);
            bool pred = incol && (lane > rr) &&
                        iou_gt(px1, py1, px2, py2, pa,
                               cb.x, cb.y, cb.z, cb.w, ca);
            u64 bm = __ballot(pred);
            if (lane == rr) myrow = bm;
        }
        intra[base + lane] = myrow;         // coalesced b64 store
    }
    __syncthreads();

    // ---- phase 6: chunked greedy (bitops serial) + readlane apply ----
    for (int t = 0; t < nchunk; ++t) {
        if (wid == 0) {
            int r = (t << 6) + lane;
            bool valid = (r < meff) && !((remv[t] >> lane) & 1ULL);
            u64 pending = __ballot(valid);
            u64 mr = intra[r];
            unsigned mlo = (unsigned)mr, mhi = (unsigned)(mr >> 32);
            u64 kept = 0ULL;
            while (pending) {
                int b = __ffsll(pending) - 1;
                kept |= 1ULL << b;
                unsigned lo = (unsigned)__builtin_amdgcn_readlane((int)mlo, b);
                unsigned hi = (unsigned)__builtin_amdgcn_readlane((int)mhi, b);
                pending &= ~((((u64)hi << 32) | lo) | (1ULL << b));
            }
            if (lane == 0) keptw[t] = kept;
        }
        __syncthreads();

        u64 kept = keptw[t];
        if (kept && (t + 1 + wid) < nchunk) {
            int src = (t << 6) + lane;
            float4 cb = bxs[src];           // chunk boxes -> lane registers, once
            float ca = bar[src];
            for (int wd = t + 1 + wid; wd < nchunk; wd += 16) {
                int col = (wd << 6) + lane;
                bool alive = col < meff;
                float4 bj = bxs[col];       // own columns, 2 LDS ops per word
                float aj = bar[col];
                u64 amask = __ballot(alive);
                u64 acc = 0ULL;
                u64 bits = kept;
                while (bits) {
                    int b = __ffsll(bits) - 1;
                    bits &= bits - 1;
                    float px1 = rdlane(cb.x, b), py1 = rdlane(cb.y, b);
                    float px2 = rdlane(cb.z, b), py2 = rdlane(cb.w, b);
                    float pa  = rdlane(ca, b);
                    bool pred = alive && iou_gt(px1, py1, px2, py2, pa,
                                                bj.x, bj.y, bj.z, bj.w, aj);
                    acc |= __ballot(pred);
                    if (acc == amask) break;   // word fully suppressed
                }
                if (lane == 0 && acc) remv[wd] |= acc;
            }
        }
        __syncthreads();
    }

    // ---- phase 7: coalesced write of all NK rows ----
    size_t obase = (size_t)c * NK * 6;
    for (int f = tid; f < NK * 6; f += 1024) {
        int r = f / 6, fld = f - r * 6;
        bool kp = (r < meff) && ((keptw[r >> 6] >> (r & 63)) & 1ULL);
        float v = 0.0f;
        if (kp) {
            if (fld == 0) v = bxs[r].x;
            else if (fld == 1) v = bxs[r].y;
            else if (fld == 2) v = bxs[r].z;
            else if (fld == 3) v = bxs[r].w;
            else if (fld == 4) v = ssc[r];
            else v = (float)c;
        }
        out[obase + f] = v;
    }
}

extern "C" void kernel_launch(void* const* d_in, const int* in_sizes, int n_in,
                              void* d_out, int out_size, void* d_ws, size_t ws_size,
                              hipStream_t stream) {
    const float* cls = (const float*)d_in[0];   // [1, A, C]
    const float4* reg = (const float4*)d_in[1]; // [1, A, 4]
    const float4* anc = (const float4*)d_in[2]; // [1, A, 4]
    float* out = (float*)d_out;                 // [C*K, 6]

    char* ws = (char*)d_ws;
    int* bcnt = (int*)(ws + 0);
    u64* vkey = (u64*)(ws + 4096);

    k_scan<<<NSEG, 1024, 0, stream>>>(cls, bcnt, vkey);
    k_nms<<<NC, 1024, 0, stream>>>(bcnt, vkey, anc, reg, out);
}

// Round 11
// 166.689 us; speedup vs baseline: 1.9424x; 1.9424x over previous
//
#include <hip/hip_runtime.h>

#pragma clang fp contract(off)

#define NA 131072
#define NC 8
#define NK 2048
#define CAP 8192       // max keys per class = NSEG*SEGC
#define NSEG 128       // scan blocks / per-class segments
#define SEGC 64        // per-segment key capacity (mean ~10, +17 sigma)
#define NW 32
#define NB 256         // rank buckets (164 used by score range)
#define CONF 0.99f
#define IMGW 320.0f
#define IMGH 256.0f

typedef unsigned long long u64;

// ---------------- ws layout (bytes) ----------------
// bcnt  : NC*NSEG int      @ 0        (4 KB)
// meffs : NC int           @ 4096     (128 B, padded region to 8192)
// vkey  : NC*NSEG*SEGC u64 @ 8192     (512 KB) -> ends 532480
// sbox  : NC*NK float4     @ 532480   (256 KB) -> ends 794624
// sar   : NC*NK float      @ 794624   (64 KB)  -> ends 860160
// ssc   : NC*NK float      @ 860160   (64 KB)  -> ends 925696
// maskT : NC*NW*NK u64     @ 925696   (4 MB)   -> ends 5120000

__device__ __forceinline__ int bucket_of(unsigned sb) {
    int d = (int)(0x3F800000u - sb);
    return min(max(d >> 10, 0), NB - 1);
}

// Exact-decision IoU > 0.5, usually division-free (absmax 0.0 r4-r10).
__device__ __forceinline__ bool iou_gt(float bix, float biy, float biz, float biw, float ai,
                                       float bjx, float bjy, float bjz, float bjw, float aj) {
    float xx1 = fmaxf(bix, bjx), yy1 = fmaxf(biy, bjy);
    float xx2 = fminf(biz, bjz), yy2 = fminf(biw, bjw);
    float inter = fmaxf(xx2 - xx1, 0.0f) * fmaxf(yy2 - yy1, 0.0f);
    float uni = (ai + aj) - inter;
    float th = 0.5f * uni;
    float diff = inter - th;
    bool pred = diff > 0.0f;
    if (__builtin_expect((uni < 1e-8f) || (pred && diff < th * 1e-6f), 0)) {
        pred = (inter / fmaxf(uni, 1e-8f)) > 0.5f;
    }
    return pred;
}

// ---------------- K1: atomic-free scan (r10, proven) ----------------
__global__ __launch_bounds__(1024) void k_scan(const float* __restrict__ cls,
                                               int* __restrict__ bcnt,
                                               u64* __restrict__ vkey) {
    __shared__ int wcnt[NC][16];
    __shared__ int woff[NC][16];
    int tid = threadIdx.x;
    int lane = tid & 63;
    int wid = tid >> 6;
    int a = blockIdx.x * 1024 + tid;

    const float4* c4 = (const float4*)(cls + (size_t)a * NC);
    float4 s0 = c4[0], s1 = c4[1];
    float sc[8] = {s0.x, s0.y, s0.z, s0.w, s1.x, s1.y, s1.z, s1.w};

    bool hit[NC];
    int off[NC];
    #pragma unroll
    for (int c = 0; c < NC; ++c) {
        bool p = sc[c] > CONF;
        u64 m = __ballot(p);
        hit[c] = p;
        off[c] = (int)__popcll(m & ((1ULL << lane) - 1ULL));
        if (lane == 0) wcnt[c][wid] = (int)__popcll(m);
    }
    __syncthreads();

    if (wid < NC) {
        int c = wid;
        int v = (lane < 16) ? wcnt[c][lane] : 0;
        #pragma unroll
        for (int d = 1; d < 16; d <<= 1) {
            int y = __shfl_up(v, d);
            if (lane >= d) v += y;
        }
        if (lane < 16) woff[c][lane] = v - wcnt[c][lane];
        if (lane == 15) bcnt[c * NSEG + blockIdx.x] = min(v, SEGC);
    }
    __syncthreads();

    #pragma unroll
    for (int c = 0; c < NC; ++c) {
        if (hit[c]) {
            int pos = woff[c][wid] + off[c];
            if (pos < SEGC) {
                vkey[((size_t)c * NSEG + blockIdx.x) * SEGC + pos] =
                    ((u64)__float_as_uint(sc[c]) << 32) | (unsigned)(~a);
            }
        }
    }
}

// ---------------- K2: counting-rank + decode (r10 phases 0-4) ----------------
__global__ __launch_bounds__(1024) void k_rank(const int* __restrict__ bcnt,
                                               const u64* __restrict__ vkey,
                                               const float4* __restrict__ anc,
                                               const float4* __restrict__ reg,
                                               float4* __restrict__ sbox,
                                               float* __restrict__ sar,
                                               float* __restrict__ ssc,
                                               int* __restrict__ meffs) {
    __shared__ u64 skv[CAP];        // 64 KB
    __shared__ int segcnt[NSEG];
    __shared__ int hist[NB];
    __shared__ int basep[NB];
    __shared__ int bcnt2[NB];
    __shared__ int M_sh;

    int c = blockIdx.x;
    int tid = threadIdx.x;
    int lane = tid & 63;
    int wid = tid >> 6;

    if (tid < NSEG) segcnt[tid] = bcnt[c * NSEG + tid];
    for (int i = tid; i < NB; i += 1024) { hist[i] = 0; bcnt2[i] = 0; }
    __syncthreads();

    for (int s = wid; s < NSEG; s += 16) {
        if (lane < segcnt[s]) {
            u64 ke = vkey[((size_t)c * NSEG + s) * SEGC + lane];
            atomicAdd(&hist[bucket_of((unsigned)(ke >> 32))], 1);
        }
    }
    __syncthreads();

    if (wid == 0) {
        int h0 = hist[4 * lane + 0], h1 = hist[4 * lane + 1];
        int h2 = hist[4 * lane + 2], h3 = hist[4 * lane + 3];
        int lsum = h0 + h1 + h2 + h3;
        int x = lsum;
        #pragma unroll
        for (int d = 1; d < 64; d <<= 1) {
            int y = __shfl_up(x, d);
            if (lane >= d) x += y;
        }
        int excl = x - lsum;
        basep[4 * lane + 0] = excl;
        basep[4 * lane + 1] = excl + h0;
        basep[4 * lane + 2] = excl + h0 + h1;
        basep[4 * lane + 3] = excl + h0 + h1 + h2;
        if (lane == 63) M_sh = x;
    }
    __syncthreads();
    int M = M_sh;
    int meff = min(M, NK);
    if (tid == 0) meffs[c] = meff;

    for (int s = wid; s < NSEG; s += 16) {
        if (lane < segcnt[s]) {
            u64 ke = vkey[((size_t)c * NSEG + s) * SEGC + lane];
            int b = bucket_of((unsigned)(ke >> 32));
            int pos = basep[b] + atomicAdd(&bcnt2[b], 1);
            skv[pos] = ke;
        }
    }
    __syncthreads();

    for (int p = tid; p < M; p += 1024) {
        u64 ke = skv[p];
        int b = bucket_of((unsigned)(ke >> 32));
        int st = basep[b], ln = hist[b];
        int rank = st;
        for (int q = st; q < st + ln; ++q) rank += (skv[q] > ke);
        if (rank < NK) {
            int idx = (int)(~(unsigned)ke);
            float4 av = anc[idx];
            float4 rv = reg[idx];
            float wa = av.z - av.x, ha = av.w - av.y;
            float cxa = av.x + 0.5f * wa, cya = av.y + 0.5f * ha;
            float dx = rv.x * 0.1f, dy = rv.y * 0.1f;
            float dw = rv.z * 0.2f, dh = rv.w * 0.2f;
            float pcx = cxa + dx * wa, pcy = cya + dy * ha;
            float pw = expf(dw) * wa, ph = expf(dh) * ha;
            float4 bb;
            bb.x = fmaxf(pcx - 0.5f * pw, 0.0f);
            bb.y = fmaxf(pcy - 0.5f * ph, 0.0f);
            bb.z = fminf(pcx + 0.5f * pw, IMGW);
            bb.w = fminf(pcy + 0.5f * ph, IMGH);
            sbox[c * NK + rank] = bb;
            sar[c * NK + rank] = fmaxf(bb.z - bb.x, 0.0f) * fmaxf(bb.w - bb.y, 0.0f);
            ssc[c * NK + rank] = __uint_as_float((unsigned)(ke >> 32));
        }
    }
}

// ---------------- K3: full transposed mask matrix, 256 blocks ----------------
__global__ __launch_bounds__(1024) void k_maskT(const int* __restrict__ meffs,
                                                const float4* __restrict__ sbox,
                                                const float* __restrict__ sar,
                                                u64* __restrict__ maskT) {
    __shared__ float4 bx[NK];
    __shared__ float ba[NK];
    int c = blockIdx.y, t = blockIdx.x;
    int meff = meffs[c];
    if (t * 64 >= meff) return;   // uniform: before any barrier
    int tid = threadIdx.x, lane = tid & 63, wid = tid >> 6;
    for (int r = tid; r < meff; r += 1024) {
        bx[r] = sbox[c * NK + r];
        ba[r] = sar[c * NK + r];
    }
    __syncthreads();
    int nchunk = (meff + 63) >> 6;
    #pragma unroll
    for (int k = 0; k < 4; ++k) {
        int r = t * 64 + wid * 4 + k;     // uniform per wave
        if (r >= meff) break;
        float4 bi = bx[r];
        float ai = ba[r];
        for (int W = t; W < nchunk; ++W) {
            int col = W * 64 + lane;
            bool pred = false;
            if (col > r && col < meff) {
                float4 bj = bx[col];
                pred = iou_gt(bi.x, bi.y, bi.z, bi.w, ai,
                              bj.x, bj.y, bj.z, bj.w, ba[col]);
            }
            u64 m = __ballot(pred);
            if (lane == 0) maskT[((size_t)(c * NW + W)) * NK + r] = m;
        }
    }
}

// ---------------- K4: transposed merge (greedy + column-OR apply) ----------------
__global__ __launch_bounds__(1024) void k_merge(const int* __restrict__ meffs,
                                                const float4* __restrict__ sbox,
                                                const float* __restrict__ ssc,
                                                const u64* __restrict__ maskT,
                                                float* __restrict__ out) {
    __shared__ u64 keptw[NW];
    __shared__ u64 remv[NW];
    int c = blockIdx.x;
    int tid = threadIdx.x, lane = tid & 63, wid = tid >> 6;
    int meff = meffs[c];
    int nchunk = (meff + 63) >> 6;
    if (tid < NW) { keptw[tid] = 0ULL; remv[tid] = 0ULL; }
    __syncthreads();

    const u64* mt = maskT + (size_t)c * NW * NK;
    int wd0 = wid, wd1 = wid + 16;   // words owned by this wave

    // prefetch for t = 0 (rows 0..63)
    u64 m0 = (wd0 > 0 && wd0 < nchunk) ? mt[(size_t)wd0 * NK + lane] : 0ULL;
    u64 m1 = (wd1 < nchunk) ? mt[(size_t)wd1 * NK + lane] : 0ULL;
    u64 diag = (wid == 0 && nchunk > 0) ? mt[lane] : 0ULL;

    for (int t = 0; t < nchunk; ++t) {
        if (wid == 0) {   // serial greedy, all in registers
            int r = (t << 6) + lane;
            bool valid = (r < meff) && !((remv[t] >> lane) & 1ULL);
            u64 pending = __ballot(valid);
            unsigned mlo = (unsigned)diag, mhi = (unsigned)(diag >> 32);
            u64 kept = 0ULL;
            while (pending) {
                int b = __ffsll(pending) - 1;
                kept |= 1ULL << b;
                unsigned lo = (unsigned)__builtin_amdgcn_readlane((int)mlo, b);
                unsigned hi = (unsigned)__builtin_amdgcn_readlane((int)mhi, b);
                pending &= ~((((u64)hi << 32) | lo) | (1ULL << b));
            }
            if (lane == 0) keptw[t] = kept;
        }
        __syncthreads();

        u64 kept = keptw[t];
        // contributions: lane holds maskT[wd][chunk-t row 'lane']
        u64 c0 = ((kept >> lane) & 1ULL) ? m0 : 0ULL;
        u64 c1 = ((kept >> lane) & 1ULL) ? m1 : 0ULL;

        // prefetch for t+1 while reducing (hides HBM/L2 latency)
        int tn = t + 1;
        if (tn < nchunk) {
            m0 = (wd0 > tn && wd0 < nchunk) ? mt[(size_t)wd0 * NK + (tn << 6) + lane] : 0ULL;
            m1 = (wd1 > tn && wd1 < nchunk) ? mt[(size_t)wd1 * NK + (tn << 6) + lane] : 0ULL;
            if (wid == 0) diag = mt[(size_t)tn * NK + (tn << 6) + lane];
        }

        // 64-lane OR-reduce of c0/c1 (butterfly on 32-bit halves)
        unsigned l0 = (unsigned)c0, h0 = (unsigned)(c0 >> 32);
        unsigned l1 = (unsigned)c1, h1 = (unsigned)(c1 >> 32);
        #pragma unroll
        for (int d = 1; d < 64; d <<= 1) {
            l0 |= (unsigned)__shfl_xor((int)l0, d);
            h0 |= (unsigned)__shfl_xor((int)h0, d);
            l1 |= (unsigned)__shfl_xor((int)l1, d);
            h1 |= (unsigned)__shfl_xor((int)h1, d);
        }
        if (lane == 0) {
            u64 r0 = ((u64)h0 << 32) | l0;
            u64 r1 = ((u64)h1 << 32) | l1;
            if (r0) remv[wd0] |= r0;
            if (r1) remv[wd1] |= r1;
        }
        __syncthreads();
    }

    // write all NK rows for this class (kept -> data, else zeros)
    size_t obase = (size_t)c * NK * 6;
    for (int f = tid; f < NK * 6; f += 1024) {
        int r = f / 6, fld = f - r * 6;
        bool kp = (r < meff) && ((keptw[r >> 6] >> (r & 63)) & 1ULL);
        float v = 0.0f;
        if (kp) {
            if (fld == 4) v = ssc[c * NK + r];
            else if (fld == 5) v = (float)c;
            else {
                float4 b = sbox[c * NK + r];
                v = (fld == 0) ? b.x : (fld == 1) ? b.y : (fld == 2) ? b.z : b.w;
            }
        }
        out[obase + f] = v;
    }
}

extern "C" void kernel_launch(void* const* d_in, const int* in_sizes, int n_in,
                              void* d_out, int out_size, void* d_ws, size_t ws_size,
                              hipStream_t stream) {
    const float* cls = (const float*)d_in[0];   // [1, A, C]
    const float4* reg = (const float4*)d_in[1]; // [1, A, 4]
    const float4* anc = (const float4*)d_in[2]; // [1, A, 4]
    float* out = (float*)d_out;                 // [C*K, 6]

    char* ws = (char*)d_ws;
    int* bcnt = (int*)(ws + 0);
    int* meffs = (int*)(ws + 4096);
    u64* vkey = (u64*)(ws + 8192);
    float4* sbox = (float4*)(ws + 532480);
    float* sar = (float*)(ws + 794624);
    float* ssc = (float*)(ws + 860160);
    u64* maskT = (u64*)(ws + 925696);

    k_scan<<<NSEG, 1024, 0, stream>>>(cls, bcnt, vkey);
    k_rank<<<NC, 1024, 0, stream>>>(bcnt, vkey, anc, reg, sbox, sar, ssc, meffs);
    k_maskT<<<dim3(NW, NC), 1024, 0, stream>>>(meffs, sbox, sar, maskT);
    k_merge<<<NC, 1024, 0, stream>>>(meffs, sbox, ssc, maskT, out);
}

// Round 12
// 162.150 us; speedup vs baseline: 1.9967x; 1.0280x over previous
//
#include <hip/hip_runtime.h>

#pragma clang fp contract(off)

#define NA 131072
#define NC 8
#define NK 2048
#define CAP 8192       // max keys per class = NSEG*SEGC
#define NSEG 128       // scan blocks / per-class segments
#define SEGC 64        // per-segment key capacity (mean ~10, +17 sigma)
#define NW 32
#define NB 256         // rank buckets (164 used by score range)
#define CONF 0.99f
#define IMGW 320.0f
#define IMGH 256.0f

typedef unsigned long long u64;

// ---------------- ws layout (bytes) ----------------
// bcnt  : NC*NSEG int      @ 0        (4 KB)
// meffs : NC int           @ 4096     (128 B, region padded to 8192)
// vkey  : NC*NSEG*SEGC u64 @ 8192     (512 KB) -> ends 532480
// sbox  : NC*NK float4     @ 532480   (256 KB) -> ends 794624
// sar   : NC*NK float      @ 794624   (64 KB)  -> ends 860160
// ssc   : NC*NK float      @ 860160   (64 KB)  -> ends 925696
// cmask : NC*NW*NK u64     @ 925696   (4 MB)   -> ends 5120000
// cmask[c][t][col] bit b = (row t*64+b suppresses col), col-major words.

__device__ __forceinline__ int bucket_of(unsigned sb) {
    int d = (int)(0x3F800000u - sb);
    return min(max(d >> 10, 0), NB - 1);
}

// Exact-decision IoU > 0.5, usually division-free (absmax 0.0 r4-r11).
__device__ __forceinline__ bool iou_gt(float bix, float biy, float biz, float biw, float ai,
                                       float bjx, float bjy, float bjz, float bjw, float aj) {
    float xx1 = fmaxf(bix, bjx), yy1 = fmaxf(biy, bjy);
    float xx2 = fminf(biz, bjz), yy2 = fminf(biw, bjw);
    float inter = fmaxf(xx2 - xx1, 0.0f) * fmaxf(yy2 - yy1, 0.0f);
    float uni = (ai + aj) - inter;
    float th = 0.5f * uni;
    float diff = inter - th;
    bool pred = diff > 0.0f;
    if (__builtin_expect((uni < 1e-8f) || (pred && diff < th * 1e-6f), 0)) {
        pred = (inter / fmaxf(uni, 1e-8f)) > 0.5f;
    }
    return pred;
}

// ---------------- K1: atomic-free scan (r10/r11, proven) ----------------
__global__ __launch_bounds__(1024) void k_scan(const float* __restrict__ cls,
                                               int* __restrict__ bcnt,
                                               u64* __restrict__ vkey) {
    __shared__ int wcnt[NC][16];
    __shared__ int woff[NC][16];
    int tid = threadIdx.x;
    int lane = tid & 63;
    int wid = tid >> 6;
    int a = blockIdx.x * 1024 + tid;

    const float4* c4 = (const float4*)(cls + (size_t)a * NC);
    float4 s0 = c4[0], s1 = c4[1];
    float sc[8] = {s0.x, s0.y, s0.z, s0.w, s1.x, s1.y, s1.z, s1.w};

    bool hit[NC];
    int off[NC];
    #pragma unroll
    for (int c = 0; c < NC; ++c) {
        bool p = sc[c] > CONF;
        u64 m = __ballot(p);
        hit[c] = p;
        off[c] = (int)__popcll(m & ((1ULL << lane) - 1ULL));
        if (lane == 0) wcnt[c][wid] = (int)__popcll(m);
    }
    __syncthreads();

    if (wid < NC) {
        int c = wid;
        int v = (lane < 16) ? wcnt[c][lane] : 0;
        #pragma unroll
        for (int d = 1; d < 16; d <<= 1) {
            int y = __shfl_up(v, d);
            if (lane >= d) v += y;
        }
        if (lane < 16) woff[c][lane] = v - wcnt[c][lane];
        if (lane == 15) bcnt[c * NSEG + blockIdx.x] = min(v, SEGC);
    }
    __syncthreads();

    #pragma unroll
    for (int c = 0; c < NC; ++c) {
        if (hit[c]) {
            int pos = woff[c][wid] + off[c];
            if (pos < SEGC) {
                vkey[((size_t)c * NSEG + blockIdx.x) * SEGC + pos] =
                    ((u64)__float_as_uint(sc[c]) << 32) | (unsigned)(~a);
            }
        }
    }
}

// ---------------- K2: counting-rank + decode (r11, proven) ----------------
__global__ __launch_bounds__(1024) void k_rank(const int* __restrict__ bcnt,
                                               const u64* __restrict__ vkey,
                                               const float4* __restrict__ anc,
                                               const float4* __restrict__ reg,
                                               float4* __restrict__ sbox,
                                               float* __restrict__ sar,
                                               float* __restrict__ ssc,
                                               int* __restrict__ meffs) {
    __shared__ u64 skv[CAP];        // 64 KB
    __shared__ int segcnt[NSEG];
    __shared__ int hist[NB];
    __shared__ int basep[NB];
    __shared__ int bcnt2[NB];
    __shared__ int M_sh;

    int c = blockIdx.x;
    int tid = threadIdx.x;
    int lane = tid & 63;
    int wid = tid >> 6;

    if (tid < NSEG) segcnt[tid] = bcnt[c * NSEG + tid];
    for (int i = tid; i < NB; i += 1024) { hist[i] = 0; bcnt2[i] = 0; }
    __syncthreads();

    for (int s = wid; s < NSEG; s += 16) {
        if (lane < segcnt[s]) {
            u64 ke = vkey[((size_t)c * NSEG + s) * SEGC + lane];
            atomicAdd(&hist[bucket_of((unsigned)(ke >> 32))], 1);
        }
    }
    __syncthreads();

    if (wid == 0) {
        int h0 = hist[4 * lane + 0], h1 = hist[4 * lane + 1];
        int h2 = hist[4 * lane + 2], h3 = hist[4 * lane + 3];
        int lsum = h0 + h1 + h2 + h3;
        int x = lsum;
        #pragma unroll
        for (int d = 1; d < 64; d <<= 1) {
            int y = __shfl_up(x, d);
            if (lane >= d) x += y;
        }
        int excl = x - lsum;
        basep[4 * lane + 0] = excl;
        basep[4 * lane + 1] = excl + h0;
        basep[4 * lane + 2] = excl + h0 + h1;
        basep[4 * lane + 3] = excl + h0 + h1 + h2;
        if (lane == 63) M_sh = x;
    }
    __syncthreads();
    int M = M_sh;
    int meff = min(M, NK);
    if (tid == 0) meffs[c] = meff;

    for (int s = wid; s < NSEG; s += 16) {
        if (lane < segcnt[s]) {
            u64 ke = vkey[((size_t)c * NSEG + s) * SEGC + lane];
            int b = bucket_of((unsigned)(ke >> 32));
            int pos = basep[b] + atomicAdd(&bcnt2[b], 1);
            skv[pos] = ke;
        }
    }
    __syncthreads();

    for (int p = tid; p < M; p += 1024) {
        u64 ke = skv[p];
        int b = bucket_of((unsigned)(ke >> 32));
        int st = basep[b], ln = hist[b];
        int rank = st;
        for (int q = st; q < st + ln; ++q) rank += (skv[q] > ke);
        if (rank < NK) {
            int idx = (int)(~(unsigned)ke);
            float4 av = anc[idx];
            float4 rv = reg[idx];
            float wa = av.z - av.x, ha = av.w - av.y;
            float cxa = av.x + 0.5f * wa, cya = av.y + 0.5f * ha;
            float dx = rv.x * 0.1f, dy = rv.y * 0.1f;
            float dw = rv.z * 0.2f, dh = rv.w * 0.2f;
            float pcx = cxa + dx * wa, pcy = cya + dy * ha;
            float pw = expf(dw) * wa, ph = expf(dh) * ha;
            float4 bb;
            bb.x = fmaxf(pcx - 0.5f * pw, 0.0f);
            bb.y = fmaxf(pcy - 0.5f * ph, 0.0f);
            bb.z = fminf(pcx + 0.5f * pw, IMGW);
            bb.w = fminf(pcy + 0.5f * ph, IMGH);
            sbox[c * NK + rank] = bb;
            sar[c * NK + rank] = fmaxf(bb.z - bb.x, 0.0f) * fmaxf(bb.w - bb.y, 0.0f);
            ssc[c * NK + rank] = __uint_as_float((unsigned)(ke >> 32));
        }
    }
}

// ---------------- K3: column-major suppression words, 256 blocks ----------------
// Block (cc, c) handles cols [cc*64, cc*64+64); per wave 4 cols; per col,
// loop row-words t=0..cc; lane = row bit; ballot -> cmask[c][t][col].
__global__ __launch_bounds__(1024) void k_cmask(const int* __restrict__ meffs,
                                                const float4* __restrict__ sbox,
                                                const float* __restrict__ sar,
                                                u64* __restrict__ cmask) {
    __shared__ float4 bx[NK];
    __shared__ float ba[NK];
    int c = blockIdx.y, cc = blockIdx.x;
    int meff = meffs[c];
    if (cc * 64 >= meff) return;   // uniform: before any barrier
    int tid = threadIdx.x, lane = tid & 63, wid = tid >> 6;
    for (int r = tid; r < meff; r += 1024) {
        bx[r] = sbox[c * NK + r];
        ba[r] = sar[c * NK + r];
    }
    __syncthreads();
    u64* cm = cmask + (size_t)c * NW * NK;
    #pragma unroll
    for (int k = 0; k < 4; ++k) {
        int col = cc * 64 + wid * 4 + k;   // uniform per wave
        if (col >= meff) break;
        float4 bc = bx[col];
        float ac = ba[col];
        for (int t = 0; t <= cc; ++t) {
            int row = t * 64 + lane;
            bool pred = false;
            if (row < col) {
                float4 br = bx[row];
                pred = iou_gt(br.x, br.y, br.z, br.w, ba[row],
                              bc.x, bc.y, bc.z, bc.w, ac);
            }
            u64 m = __ballot(pred);
            if (lane == 0) cm[(size_t)t * NK + col] = m;
        }
    }
}

// ---------------- K4: merge — replicated bitops greedy + ballot apply ----------------
// One barrier per chunk. Each thread owns 2 columns; apply is
// load (prefetched) + AND + ballot; greedy replicated per wave from diag.
__global__ __launch_bounds__(1024) void k_merge(const int* __restrict__ meffs,
                                                const float4* __restrict__ sbox,
                                                const float* __restrict__ ssc,
                                                const u64* __restrict__ cmask,
                                                float* __restrict__ out) {
    __shared__ u64 keptw[NW];
    __shared__ u64 remv[NW];
    int c = blockIdx.x;
    int tid = threadIdx.x, lane = tid & 63, wid = tid >> 6;
    int meff = meffs[c];
    int nchunk = (meff + 63) >> 6;
    if (tid < NW) { keptw[tid] = 0ULL; remv[tid] = 0ULL; }
    __syncthreads();

    const u64* cm = cmask + (size_t)c * NW * NK;
    int col0 = tid, col1 = tid + 1024;
    int wd0 = wid, wd1 = wid + 16;
    bool alive0 = col0 < meff, alive1 = col1 < meff;

    // preload chunk 0
    u64 dg = 0, cw0 = 0, cw1 = 0;
    if (nchunk > 0) {
        dg = cm[lane];
        if (wd0 > 0 && wd0 < nchunk) cw0 = cm[col0];
        if (wd1 < nchunk) cw1 = cm[col1];
    }

    for (int t = 0; t < nchunk; ++t) {
        u64 rt = remv[t];   // finalized by barrier of iteration t-1
        // replicated greedy on the diagonal word (registers + ballots only)
        bool valid = ((t << 6) + lane) < meff && !((rt >> lane) & 1ULL);
        u64 pending = __ballot(valid);
        u64 kept = 0ULL;
        while (pending) {
            int b = __ffsll(pending) - 1;
            kept |= 1ULL << b;
            u64 sm = __ballot((dg >> b) & 1ULL);
            pending &= ~(sm | (1ULL << b));
        }
        if (tid == 0) keptw[t] = kept;

        // apply to own columns (words > t): sup iff any kept row hits col
        bool s0 = (wd0 > t) && alive0 && ((cw0 & kept) != 0ULL);
        bool s1 = (wd1 > t) && alive1 && ((cw1 & kept) != 0ULL);
        u64 bm0 = __ballot(s0);
        u64 bm1 = __ballot(s1);
        if (lane == 0) {
            if (bm0) remv[wd0] |= bm0;
            if (bm1) remv[wd1] |= bm1;
        }

        // prefetch chunk t+1 (hidden under next barrier/greedy)
        int tn = t + 1;
        if (tn < nchunk) {
            dg = cm[(size_t)tn * NK + (tn << 6) + lane];
            cw0 = (wd0 > tn) ? cm[(size_t)tn * NK + col0] : 0ULL;
            cw1 = (wd1 > tn && wd1 < nchunk) ? cm[(size_t)tn * NK + col1] : 0ULL;
        }
        __syncthreads();
    }

    // write all NK rows for this class (kept -> data, else zeros)
    size_t obase = (size_t)c * NK * 6;
    for (int f = tid; f < NK * 6; f += 1024) {
        int r = f / 6, fld = f - r * 6;
        bool kp = (r < meff) && ((keptw[r >> 6] >> (r & 63)) & 1ULL);
        float v = 0.0f;
        if (kp) {
            if (fld == 4) v = ssc[c * NK + r];
            else if (fld == 5) v = (float)c;
            else {
                float4 b = sbox[c * NK + r];
                v = (fld == 0) ? b.x : (fld == 1) ? b.y : (fld == 2) ? b.z : b.w;
            }
        }
        out[obase + f] = v;
    }
}

extern "C" void kernel_launch(void* const* d_in, const int* in_sizes, int n_in,
                              void* d_out, int out_size, void* d_ws, size_t ws_size,
                              hipStream_t stream) {
    const float* cls = (const float*)d_in[0];   // [1, A, C]
    const float4* reg = (const float4*)d_in[1]; // [1, A, 4]
    const float4* anc = (const float4*)d_in[2]; // [1, A, 4]
    float* out = (float*)d_out;                 // [C*K, 6]

    char* ws = (char*)d_ws;
    int* bcnt = (int*)(ws + 0);
    int* meffs = (int*)(ws + 4096);
    u64* vkey = (u64*)(ws + 8192);
    float4* sbox = (float4*)(ws + 532480);
    float* sar = (float*)(ws + 794624);
    float* ssc = (float*)(ws + 860160);
    u64* cmask = (u64*)(ws + 925696);

    k_scan<<<NSEG, 1024, 0, stream>>>(cls, bcnt, vkey);
    k_rank<<<NC, 1024, 0, stream>>>(bcnt, vkey, anc, reg, sbox, sar, ssc, meffs);
    k_cmask<<<dim3(NW, NC), 1024, 0, stream>>>(meffs, sbox, sar, cmask);
    k_merge<<<NC, 1024, 0, stream>>>(meffs, sbox, ssc, cmask, out);
}

// Round 13
// 121.096 us; speedup vs baseline: 2.6737x; 1.3390x over previous
//
#include <hip/hip_runtime.h>

#pragma clang fp contract(off)

#define NA 131072
#define NC 8
#define NK 2048
#define CAP 8192       // max keys per class = NSEG*SEGC
#define NSEG 128       // scan blocks / per-class segments
#define SEGC 64        // per-segment key capacity (mean ~10, +17 sigma)
#define NW 32
#define NB 256         // rank buckets (164 used by score range)
#define CONF 0.99f
#define IMGW 320.0f
#define IMGH 256.0f

typedef unsigned long long u64;

// ---------------- ws layout (bytes) ----------------
// bcnt  : NC*NSEG int      @ 0        (4 KB)
// meffs : NC int           @ 4096     (128 B, region padded to 8192)
// vkey  : NC*NSEG*SEGC u64 @ 8192     (512 KB) -> ends 532480
// sbox  : NC*NK float4     @ 532480   (256 KB) -> ends 794624
// sar   : NC*NK float      @ 794624   (64 KB)  -> ends 860160
// ssc   : NC*NK float      @ 860160   (64 KB)  -> ends 925696
// cmask : NC*NW*NK u64     @ 925696   (4 MB)   -> ends 5120000
// cmask[c][t][col] bit b = (row t*64+b suppresses col), col-major words.

__device__ __forceinline__ int bucket_of(unsigned sb) {
    int d = (int)(0x3F800000u - sb);
    return min(max(d >> 10, 0), NB - 1);
}

// Exact-decision IoU > 0.5, usually division-free (absmax 0.0 r4-r12).
__device__ __forceinline__ bool iou_gt(float bix, float biy, float biz, float biw, float ai,
                                       float bjx, float bjy, float bjz, float bjw, float aj) {
    float xx1 = fmaxf(bix, bjx), yy1 = fmaxf(biy, bjy);
    float xx2 = fminf(biz, bjz), yy2 = fminf(biw, bjw);
    float inter = fmaxf(xx2 - xx1, 0.0f) * fmaxf(yy2 - yy1, 0.0f);
    float uni = (ai + aj) - inter;
    float th = 0.5f * uni;
    float diff = inter - th;
    bool pred = diff > 0.0f;
    if (__builtin_expect((uni < 1e-8f) || (pred && diff < th * 1e-6f), 0)) {
        pred = (inter / fmaxf(uni, 1e-8f)) > 0.5f;
    }
    return pred;
}

// ---------------- K1: atomic-free scan (r10-r12, proven) ----------------
__global__ __launch_bounds__(1024) void k_scan(const float* __restrict__ cls,
                                               int* __restrict__ bcnt,
                                               u64* __restrict__ vkey) {
    __shared__ int wcnt[NC][16];
    __shared__ int woff[NC][16];
    int tid = threadIdx.x;
    int lane = tid & 63;
    int wid = tid >> 6;
    int a = blockIdx.x * 1024 + tid;

    const float4* c4 = (const float4*)(cls + (size_t)a * NC);
    float4 s0 = c4[0], s1 = c4[1];
    float sc[8] = {s0.x, s0.y, s0.z, s0.w, s1.x, s1.y, s1.z, s1.w};

    bool hit[NC];
    int off[NC];
    #pragma unroll
    for (int c = 0; c < NC; ++c) {
        bool p = sc[c] > CONF;
        u64 m = __ballot(p);
        hit[c] = p;
        off[c] = (int)__popcll(m & ((1ULL << lane) - 1ULL));
        if (lane == 0) wcnt[c][wid] = (int)__popcll(m);
    }
    __syncthreads();

    if (wid < NC) {
        int c = wid;
        int v = (lane < 16) ? wcnt[c][lane] : 0;
        #pragma unroll
        for (int d = 1; d < 16; d <<= 1) {
            int y = __shfl_up(v, d);
            if (lane >= d) v += y;
        }
        if (lane < 16) woff[c][lane] = v - wcnt[c][lane];
        if (lane == 15) bcnt[c * NSEG + blockIdx.x] = min(v, SEGC);
    }
    __syncthreads();

    #pragma unroll
    for (int c = 0; c < NC; ++c) {
        if (hit[c]) {
            int pos = woff[c][wid] + off[c];
            if (pos < SEGC) {
                vkey[((size_t)c * NSEG + blockIdx.x) * SEGC + pos] =
                    ((u64)__float_as_uint(sc[c]) << 32) | (unsigned)(~a);
            }
        }
    }
}

// ---------------- K2: counting-rank + decode (r11/r12, proven) ----------------
__global__ __launch_bounds__(1024) void k_rank(const int* __restrict__ bcnt,
                                               const u64* __restrict__ vkey,
                                               const float4* __restrict__ anc,
                                               const float4* __restrict__ reg,
                                               float4* __restrict__ sbox,
                                               float* __restrict__ sar,
                                               float* __restrict__ ssc,
                                               int* __restrict__ meffs) {
    __shared__ u64 skv[CAP];        // 64 KB
    __shared__ int segcnt[NSEG];
    __shared__ int hist[NB];
    __shared__ int basep[NB];
    __shared__ int bcnt2[NB];
    __shared__ int M_sh;

    int c = blockIdx.x;
    int tid = threadIdx.x;
    int lane = tid & 63;
    int wid = tid >> 6;

    if (tid < NSEG) segcnt[tid] = bcnt[c * NSEG + tid];
    for (int i = tid; i < NB; i += 1024) { hist[i] = 0; bcnt2[i] = 0; }
    __syncthreads();

    for (int s = wid; s < NSEG; s += 16) {
        if (lane < segcnt[s]) {
            u64 ke = vkey[((size_t)c * NSEG + s) * SEGC + lane];
            atomicAdd(&hist[bucket_of((unsigned)(ke >> 32))], 1);
        }
    }
    __syncthreads();

    if (wid == 0) {
        int h0 = hist[4 * lane + 0], h1 = hist[4 * lane + 1];
        int h2 = hist[4 * lane + 2], h3 = hist[4 * lane + 3];
        int lsum = h0 + h1 + h2 + h3;
        int x = lsum;
        #pragma unroll
        for (int d = 1; d < 64; d <<= 1) {
            int y = __shfl_up(x, d);
            if (lane >= d) x += y;
        }
        int excl = x - lsum;
        basep[4 * lane + 0] = excl;
        basep[4 * lane + 1] = excl + h0;
        basep[4 * lane + 2] = excl + h0 + h1;
        basep[4 * lane + 3] = excl + h0 + h1 + h2;
        if (lane == 63) M_sh = x;
    }
    __syncthreads();
    int M = M_sh;
    int meff = min(M, NK);
    if (tid == 0) meffs[c] = meff;

    for (int s = wid; s < NSEG; s += 16) {
        if (lane < segcnt[s]) {
            u64 ke = vkey[((size_t)c * NSEG + s) * SEGC + lane];
            int b = bucket_of((unsigned)(ke >> 32));
            int pos = basep[b] + atomicAdd(&bcnt2[b], 1);
            skv[pos] = ke;
        }
    }
    __syncthreads();

    for (int p = tid; p < M; p += 1024) {
        u64 ke = skv[p];
        int b = bucket_of((unsigned)(ke >> 32));
        int st = basep[b], ln = hist[b];
        int rank = st;
        for (int q = st; q < st + ln; ++q) rank += (skv[q] > ke);
        if (rank < NK) {
            int idx = (int)(~(unsigned)ke);
            float4 av = anc[idx];
            float4 rv = reg[idx];
            float wa = av.z - av.x, ha = av.w - av.y;
            float cxa = av.x + 0.5f * wa, cya = av.y + 0.5f * ha;
            float dx = rv.x * 0.1f, dy = rv.y * 0.1f;
            float dw = rv.z * 0.2f, dh = rv.w * 0.2f;
            float pcx = cxa + dx * wa, pcy = cya + dy * ha;
            float pw = expf(dw) * wa, ph = expf(dh) * ha;
            float4 bb;
            bb.x = fmaxf(pcx - 0.5f * pw, 0.0f);
            bb.y = fmaxf(pcy - 0.5f * ph, 0.0f);
            bb.z = fminf(pcx + 0.5f * pw, IMGW);
            bb.w = fminf(pcy + 0.5f * ph, IMGH);
            sbox[c * NK + rank] = bb;
            sar[c * NK + rank] = fmaxf(bb.z - bb.x, 0.0f) * fmaxf(bb.w - bb.y, 0.0f);
            ssc[c * NK + rank] = __uint_as_float((unsigned)(ke >> 32));
        }
    }
}

// ---------------- K3: column-major suppression words, 256 blocks ----------------
__global__ __launch_bounds__(1024) void k_cmask(const int* __restrict__ meffs,
                                                const float4* __restrict__ sbox,
                                                const float* __restrict__ sar,
                                                u64* __restrict__ cmask) {
    __shared__ float4 bx[NK];
    __shared__ float ba[NK];
    int c = blockIdx.y, cc = blockIdx.x;
    int meff = meffs[c];
    if (cc * 64 >= meff) return;   // uniform: before any barrier
    int tid = threadIdx.x, lane = tid & 63, wid = tid >> 6;
    for (int r = tid; r < meff; r += 1024) {
        bx[r] = sbox[c * NK + r];
        ba[r] = sar[c * NK + r];
    }
    __syncthreads();
    u64* cm = cmask + (size_t)c * NW * NK;
    #pragma unroll
    for (int k = 0; k < 4; ++k) {
        int col = cc * 64 + wid * 4 + k;   // uniform per wave
        if (col >= meff) break;
        float4 bc = bx[col];
        float ac = ba[col];
        for (int t = 0; t <= cc; ++t) {
            int row = t * 64 + lane;
            bool pred = false;
            if (row < col) {
                float4 br = bx[row];
                pred = iou_gt(br.x, br.y, br.z, br.w, ba[row],
                              bc.x, bc.y, bc.z, bc.w, ac);
            }
            u64 m = __ballot(pred);
            if (lane == 0) cm[(size_t)t * NK + col] = m;
        }
    }
}

// ---------------- K4: merge — fixpoint greedy + ballot apply ----------------
// Greedy per chunk: Jacobi fixpoint kept' = ballot(valid && (kept&dg)==0).
// Any fixpoint == sequential greedy (dg holds only lower rows); converges in
// O(chain depth) iterations (~3-6) instead of ~40 serial pops.
__global__ __launch_bounds__(1024) void k_merge(const int* __restrict__ meffs,
                                                const float4* __restrict__ sbox,
                                                const float* __restrict__ ssc,
                                                const u64* __restrict__ cmask,
                                                float* __restrict__ out) {
    __shared__ u64 keptw[NW];
    __shared__ u64 remv[NW];
    int c = blockIdx.x;
    int tid = threadIdx.x, lane = tid & 63, wid = tid >> 6;
    int meff = meffs[c];
    int nchunk = (meff + 63) >> 6;
    if (tid < NW) { keptw[tid] = 0ULL; remv[tid] = 0ULL; }
    __syncthreads();

    const u64* cm = cmask + (size_t)c * NW * NK;
    int col0 = tid, col1 = tid + 1024;
    int wd0 = wid, wd1 = wid + 16;
    bool alive0 = col0 < meff, alive1 = col1 < meff;

    // preload chunk 0
    u64 dg = 0, cw0 = 0, cw1 = 0;
    if (nchunk > 0) {
        dg = cm[lane];
        if (wd0 > 0 && wd0 < nchunk) cw0 = cm[col0];
        if (wd1 < nchunk) cw1 = cm[col1];
    }

    for (int t = 0; t < nchunk; ++t) {
        // prefetch chunk t+1 FIRST: loads complete during greedy/apply, so the
        // vmcnt(0) drain at the barrier finds them done.
        u64 ndg = 0, ncw0 = 0, ncw1 = 0;
        int tn = t + 1;
        if (tn < nchunk) {
            ndg = cm[(size_t)tn * NK + (tn << 6) + lane];
            if (wd0 > tn && wd0 < nchunk) ncw0 = cm[(size_t)tn * NK + col0];
            if (wd1 > tn && wd1 < nchunk) ncw1 = cm[(size_t)tn * NK + col1];
        }

        u64 rt = remv[t];   // finalized by barrier of iteration t-1
        bool valid = (((t << 6) + lane) < meff) && !((rt >> lane) & 1ULL);

        // fixpoint greedy (replicated in every wave; all ballots wave-uniform)
        u64 kept = __ballot(valid);
        #pragma unroll 1
        for (int it = 0; it < 64; ++it) {
            u64 nk = __ballot(valid && ((kept & dg) == 0ULL));
            if (nk == kept) break;
            kept = nk;
        }
        if (tid == 0) keptw[t] = kept;

        // apply to own columns (words > t): sup iff any kept row hits col
        bool s0 = (wd0 > t) && alive0 && ((cw0 & kept) != 0ULL);
        bool s1 = (wd1 > t) && alive1 && ((cw1 & kept) != 0ULL);
        u64 bm0 = __ballot(s0);
        u64 bm1 = __ballot(s1);
        if (lane == 0) {
            if (bm0) remv[wd0] |= bm0;
            if (bm1) remv[wd1] |= bm1;
        }

        dg = ndg; cw0 = ncw0; cw1 = ncw1;
        __syncthreads();
    }

    // write all NK rows for this class (kept -> data, else zeros)
    size_t obase = (size_t)c * NK * 6;
    for (int f = tid; f < NK * 6; f += 1024) {
        int r = f / 6, fld = f - r * 6;
        bool kp = (r < meff) && ((keptw[r >> 6] >> (r & 63)) & 1ULL);
        float v = 0.0f;
        if (kp) {
            if (fld == 4) v = ssc[c * NK + r];
            else if (fld == 5) v = (float)c;
            else {
                float4 b = sbox[c * NK + r];
                v = (fld == 0) ? b.x : (fld == 1) ? b.y : (fld == 2) ? b.z : b.w;
            }
        }
        out[obase + f] = v;
    }
}

extern "C" void kernel_launch(void* const* d_in, const int* in_sizes, int n_in,
                              void* d_out, int out_size, void* d_ws, size_t ws_size,
                              hipStream_t stream) {
    const float* cls = (const float*)d_in[0];   // [1, A, C]
    const float4* reg = (const float4*)d_in[1]; // [1, A, 4]
    const float4* anc = (const float4*)d_in[2]; // [1, A, 4]
    float* out = (float*)d_out;                 // [C*K, 6]

    char* ws = (char*)d_ws;
    int* bcnt = (int*)(ws + 0);
    int* meffs = (int*)(ws + 4096);
    u64* vkey = (u64*)(ws + 8192);
    float4* sbox = (float4*)(ws + 532480);
    float* sar = (float*)(ws + 794624);
    float* ssc = (float*)(ws + 860160);
    u64* cmask = (u64*)(ws + 925696);

    k_scan<<<NSEG, 1024, 0, stream>>>(cls, bcnt, vkey);
    k_rank<<<NC, 1024, 0, stream>>>(bcnt, vkey, anc, reg, sbox, sar, ssc, meffs);
    k_cmask<<<dim3(NW, NC), 1024, 0, stream>>>(meffs, sbox, sar, cmask);
    k_merge<<<NC, 1024, 0, stream>>>(meffs, sbox, ssc, cmask, out);
}